// Round 6
// baseline (95.079 us; speedup 1.0000x reference)
//
#include <hip/hip_runtime.h>
#include <stdint.h>
#include <stddef.h>

// ---------------------------------------------------------------------------
// StructureAwareAttention  (B=2, L=1024, D=1024, H=16, HD=64)
//   prep: cvt x,sb -> bf16; transpose Wqkv/Ws/Wo -> [N][K] bf16   (1 kernel)
//   gemm01 (merged launch): qkv = x@Wqkv+bqkv -> q,k,v^T bf16 ; sw = sb@Ws+bs f32
//   attn: flash, swapped QK^T + swapped PV (lane-local state), K/V LDS-staged
//         3-buffer / 2-deep pipeline, raw s_barrier + counted vmcnt(4) (T3/T4),
//         XOR-swizzled both sides, KVBLK=64, defer-max, setprio on MFMA
//   out = ctx@Wo + bo              -> f32 [B,L,D]
// GEMMs: 64x128 tile, BK=64, 2-phase double-buffered LDS (1 barrier/K-step).
// Workspace:
//   0: xb 4MB | 4MB: sbb 4MB | 8MB: Wqkv^T 6MB | 14MB: Ws^T 2MB | 16MB: Wo^T 2MB
//   18MB: q 4MB | 22MB: k 4MB | 26MB: v^T 4MB | 30MB: sw(f32) 8MB | 38MB: ctx 4MB
// ---------------------------------------------------------------------------

typedef float f32x4 __attribute__((ext_vector_type(4)));
typedef short s16x8 __attribute__((ext_vector_type(8)));
typedef unsigned short u16x8 __attribute__((ext_vector_type(8)));
typedef unsigned short u16x4 __attribute__((ext_vector_type(4)));

__device__ inline unsigned short f2bf(float f) {          // RNE f32 -> bf16
    unsigned u = __builtin_bit_cast(unsigned, f);
    u += 0x7fffu + ((u >> 16) & 1u);
    return (unsigned short)(u >> 16);
}

__device__ inline f32x4 mfma16(s16x8 a, s16x8 b, f32x4 c) {
    return __builtin_amdgcn_mfma_f32_16x16x32_bf16(a, b, c, 0, 0, 0);
}

__device__ inline void gld_lds16(const void* g, const void* lds_base) {
    __builtin_amdgcn_global_load_lds(
        (const __attribute__((address_space(1))) void*)(uintptr_t)g,
        (__attribute__((address_space(3))) void*)(unsigned)(uintptr_t)lds_base,
        16, 0, 0);
}

// ------------------------------ prep ---------------------------------------
// blocks [0,1024): cvt x | [1024,2048): cvt sb | [2048,2816): Wqkv^T
// [2816,3072): Ws^T | [3072,3328): Wo^T
__global__ __launch_bounds__(256) void prep_k(const float* __restrict__ x,
                                              const float* __restrict__ sb,
                                              const float* __restrict__ Wqkv,
                                              const float* __restrict__ Ws,
                                              const float* __restrict__ Wo,
                                              unsigned short* __restrict__ xb,
                                              unsigned short* __restrict__ sbb,
                                              unsigned short* __restrict__ wqkvt,
                                              unsigned short* __restrict__ wst,
                                              unsigned short* __restrict__ wot) {
    __shared__ float tile[64][65];
    const int blk = blockIdx.x, t = threadIdx.x;
    if (blk < 2048) {                                   // bf16 convert, 8 elem/thread
        const float* src = (blk < 1024) ? x : sb;
        unsigned short* dst = (blk < 1024) ? xb : sbb;
        int i = (blk & 1023) * 256 + t;
        const float4* s4 = (const float4*)src;
        float4 a = s4[2 * i], b = s4[2 * i + 1];
        u16x8 o;
        o[0] = f2bf(a.x); o[1] = f2bf(a.y); o[2] = f2bf(a.z); o[3] = f2bf(a.w);
        o[4] = f2bf(b.x); o[5] = f2bf(b.y); o[6] = f2bf(b.z); o[7] = f2bf(b.w);
        *(u16x8*)(dst + (size_t)i * 8) = o;
        return;
    }
    int tt = blk - 2048;
    const float* W; unsigned short* Wt; int N, n0, k0;
    if (tt < 768)       { W = Wqkv; Wt = wqkvt; N = 3072; n0 = (tt % 48) * 64; k0 = (tt / 48) * 64; }
    else if (tt < 1024) { tt -= 768;  W = Ws; Wt = wst; N = 1024; n0 = (tt & 15) * 64; k0 = (tt >> 4) * 64; }
    else                { tt -= 1024; W = Wo; Wt = wot; N = 1024; n0 = (tt & 15) * 64; k0 = (tt >> 4) * 64; }
    const int lr = t >> 4, lc = (t & 15) * 4;
#pragma unroll
    for (int rr = 0; rr < 4; rr++) {
        int r = lr + rr * 16;
        float4 v = *(const float4*)(W + (size_t)(k0 + r) * N + n0 + lc);
        tile[r][lc] = v.x; tile[r][lc + 1] = v.y; tile[r][lc + 2] = v.z; tile[r][lc + 3] = v.w;
    }
    __syncthreads();
    const int wn = t >> 3, wk = (t & 7) * 8;
#pragma unroll
    for (int rr = 0; rr < 2; rr++) {
        int n = wn + rr * 32;
        u16x8 o;
#pragma unroll
        for (int j = 0; j < 8; j++) o[j] = f2bf(tile[wk + j][n]);
        *(u16x8*)(Wt + (size_t)(n0 + n) * 1024 + k0 + wk) = o;
    }
}

// ------------------------------- GEMM body ----------------------------------
// C[M,N] = A[M,1024] @ Bt[N,1024]^T + bias.  64x128 tile, BK=64, 4 waves,
// double-buffered LDS, 1 barrier per K-step (stage next || compute cur).
// epi 0: scatter bf16 into q/k [B,H,L,64] and v^T [B,H,64,L] (N=3072)
// epi 1: f32 row-major [M][1024]
__device__ __forceinline__ void gemm_body(const unsigned short* __restrict__ A,
                                          const unsigned short* __restrict__ Bt,
                                          const float* __restrict__ bias,
                                          int bn0, int bm0, int epi,
                                          unsigned short* __restrict__ q,
                                          unsigned short* __restrict__ kk_,
                                          unsigned short* __restrict__ vt,
                                          float* __restrict__ outf,
                                          unsigned short* lAs, unsigned short* lBs) {
    const int t = threadIdx.x;
    const int wave = t >> 6, lane = t & 63, c = lane & 15, g = lane >> 4;
    const int wc = wave * 32;

    size_t aoff[2], boff[4];
#pragma unroll
    for (int j = 0; j < 2; j++) {
        int s = j * 256 + t, row = s >> 3, ch = (s & 7) ^ (row & 7);
        aoff[j] = (size_t)(bm0 + row) * 1024 + ch * 8;
    }
#pragma unroll
    for (int j = 0; j < 4; j++) {
        int s = j * 256 + t, row = s >> 3, ch = (s & 7) ^ (row & 7);
        boff[j] = (size_t)(bn0 + row) * 1024 + ch * 8;
    }
    char* lAb0 = (char*)lAs; char* lBb0 = (char*)lBs;

#define GSTAGE(buf, kt)                                                                  \
    do {                                                                                 \
        _Pragma("unroll")                                                                \
        for (int j = 0; j < 2; j++)                                                      \
            gld_lds16(A + aoff[j] + (kt), lAb0 + (buf) * 8192 + j * 4096 + wave * 1024); \
        _Pragma("unroll")                                                                \
        for (int j = 0; j < 4; j++)                                                      \
            gld_lds16(Bt + boff[j] + (kt), lBb0 + (buf) * 16384 + j * 4096 + wave * 1024);\
    } while (0)

    f32x4 acc[4][2];
#pragma unroll
    for (int i = 0; i < 4; i++)
#pragma unroll
        for (int j = 0; j < 2; j++) acc[i][j] = {0.f, 0.f, 0.f, 0.f};

    GSTAGE(0, 0);
    for (int ks = 0; ks < 16; ++ks) {
        __syncthreads();
        if (ks < 15) GSTAGE((ks + 1) & 1, (ks + 1) * 64);
        const char* aB = lAb0 + (ks & 1) * 8192;
        const char* bB = lBb0 + (ks & 1) * 16384;
#pragma unroll
        for (int kk2 = 0; kk2 < 2; ++kk2) {
            s16x8 af[4], bfr[2];
#pragma unroll
            for (int i = 0; i < 4; i++) {
                int r_ = i * 16 + c;
                af[i] = *(const s16x8*)(aB + r_ * 128 + (((kk2 * 4 + g) ^ (r_ & 7)) << 4));
            }
#pragma unroll
            for (int j = 0; j < 2; j++) {
                int r_ = wc + j * 16 + c;
                bfr[j] = *(const s16x8*)(bB + r_ * 128 + (((kk2 * 4 + g) ^ (r_ & 7)) << 4));
            }
            __builtin_amdgcn_s_setprio(1);
#pragma unroll
            for (int i = 0; i < 4; i++)
#pragma unroll
                for (int j = 0; j < 2; j++)
                    acc[i][j] = mfma16(af[i], bfr[j], acc[i][j]);
            __builtin_amdgcn_s_setprio(0);
        }
    }
#undef GSTAGE

#pragma unroll
    for (int i = 0; i < 4; i++) {
#pragma unroll
        for (int j = 0; j < 2; j++) {
            const int n = bn0 + wc + j * 16 + c;
            const float bv = bias[n];
#pragma unroll
            for (int r = 0; r < 4; r++) {
                const int m = bm0 + i * 16 + g * 4 + r;
                float v = acc[i][j][r] + bv;
                if (epi == 0) {
                    const int sel = n >> 10, h = (n >> 6) & 15, d = n & 63;
                    const int b_ = m >> 10, l_ = m & 1023;
                    const size_t bh = (size_t)((b_ << 4) + h);
                    unsigned short hv = f2bf(v);
                    if (sel == 0)      q[(bh * 1024 + l_) * 64 + d] = hv;
                    else if (sel == 1) kk_[(bh * 1024 + l_) * 64 + d] = hv;
                    else               vt[(bh * 64 + d) * 1024 + l_] = hv;
                } else {
                    outf[(size_t)m * 1024 + n] = v;
                }
            }
        }
    }
}

// merged qkv + sw GEMM: grid (32, 32); x<24 -> qkv tile, else sw tile
__global__ __launch_bounds__(256, 3) void gemm01_k(const unsigned short* __restrict__ xb,
                                                   const unsigned short* __restrict__ wqkvt,
                                                   const float* __restrict__ bqkv,
                                                   const unsigned short* __restrict__ sbb,
                                                   const unsigned short* __restrict__ wst,
                                                   const float* __restrict__ bs,
                                                   unsigned short* __restrict__ q,
                                                   unsigned short* __restrict__ kk_,
                                                   unsigned short* __restrict__ vt,
                                                   float* __restrict__ swf) {
    __shared__ unsigned short lA[2][4096];
    __shared__ unsigned short lB[2][8192];
    const int bx = blockIdx.x, bm0 = blockIdx.y * 64;
    if (bx < 24)
        gemm_body(xb, wqkvt, bqkv, bx * 128, bm0, 0, q, kk_, vt, (float*)nullptr, lA[0], lB[0]);
    else
        gemm_body(sbb, wst, bs, (bx - 24) * 128, bm0, 1,
                  (unsigned short*)nullptr, (unsigned short*)nullptr, (unsigned short*)nullptr,
                  swf, lA[0], lB[0]);
}

// out GEMM: grid (8, 32)
__global__ __launch_bounds__(256, 3) void gemmo_k(const unsigned short* __restrict__ ctx,
                                                  const unsigned short* __restrict__ wot,
                                                  const float* __restrict__ bo,
                                                  float* __restrict__ out) {
    __shared__ unsigned short lA[2][4096];
    __shared__ unsigned short lB[2][8192];
    gemm_body(ctx, wot, bo, blockIdx.x * 128, blockIdx.y * 64, 1,
              (unsigned short*)nullptr, (unsigned short*)nullptr, (unsigned short*)nullptr,
              out, lA[0], lB[0]);
}

// ------------------------------ attention ----------------------------------
// grid 512: block = (bh, 64 q-rows), wave = 16 q-rows, full KV sweep.
// KVBLK=64, 3 LDS buffers, stage issued 2 iters ahead; raw s_barrier +
// counted vmcnt(4) so stages stay in flight across barriers (T3/T4).
// sw-bias register-prefetched 1 iter ahead (issued BEFORE the stage so its
// compiler in-order wait never drains the in-flight stages).
// Swapped QK^T + swapped PV: softmax state fully lane-local. Defer-max THR=8.
__global__ __launch_bounds__(256, 2) void attn_k(const unsigned short* __restrict__ q,
                                                 const unsigned short* __restrict__ k,
                                                 const unsigned short* __restrict__ vt,
                                                 const float* __restrict__ sw,
                                                 unsigned short* __restrict__ ctx) {
    __shared__ unsigned short kbuf[3][4096];         // [64 kv][64 hd] swizzled
    __shared__ unsigned short vbuf[3][4096];         // [64 d][64 kv] swizzled
    __shared__ unsigned short lP[4][640];            // per wave: 16 q-rows x 40 (pad)
    const int t = threadIdx.x, wave = t >> 6, lane = t & 63, c = lane & 15, g = lane >> 4;
    const int blk = blockIdx.x;
    const int qt = blk & 15, bh = blk >> 4, b_ = bh >> 4, h = bh & 15;
    const int qr = qt * 64 + wave * 16;

    const unsigned short* qbase = q + ((size_t)bh * 1024 + qr) * 64;
    s16x8 qf0 = *(const s16x8*)(qbase + (size_t)c * 64 + g * 8);
    s16x8 qf1 = *(const s16x8*)(qbase + (size_t)c * 64 + 32 + g * 8);

    const unsigned short* kg = k + (size_t)bh * 65536;     // [1024][64]
    const unsigned short* vg = vt + (size_t)bh * 65536;    // [64][1024]
    const float* swrow = sw + ((size_t)b_ * 1024 + qr + c) * 1024;

    const int s0 = wave * 128 + lane, s1 = s0 + 64;
    const int r0 = s0 >> 3, ch0 = (s0 & 7) ^ (r0 & 7);
    const int r1 = s1 >> 3, ch1 = (s1 & 7) ^ (r1 & 7);

    const float SC  = 0.125f * 1.4426950408889634f;
    const float L2E = 1.4426950408889634f;

    float mr = -1e30f, lr = 0.0f;    // state for q-row c (replicated over g)
    f32x4 acc[4];                    // acc[nf][r] = ctx^T[d = nf*16+4g+r][q = c]
#pragma unroll
    for (int nf = 0; nf < 4; nf++) acc[nf] = {0.f, 0.f, 0.f, 0.f};
    unsigned short* wp = lP[wave];
    const int swz = (c & 7);

#define STAGE(buf, kv0)                                                                     \
    do {                                                                                    \
        gld_lds16(kg + (size_t)((kv0) + r0) * 64 + ch0 * 8, (char*)kbuf[buf] + wave * 2048);            \
        gld_lds16(kg + (size_t)((kv0) + r1) * 64 + ch1 * 8, (char*)kbuf[buf] + wave * 2048 + 1024);     \
        gld_lds16(vg + (size_t)r0 * 1024 + (kv0) + ch0 * 8, (char*)vbuf[buf] + wave * 2048);            \
        gld_lds16(vg + (size_t)r1 * 1024 + (kv0) + ch1 * 8, (char*)vbuf[buf] + wave * 2048 + 1024);     \
    } while (0)

    // prologue: stage0, sw(iter0), stage1  (issue order matters for vmcnt math)
    STAGE(0, 0);
    float4 swc[4];
#pragma unroll
    for (int j = 0; j < 4; j++) swc[j] = *(const float4*)(swrow + j * 16 + 4 * g);
    STAGE(1, 64);

    for (int it = 0; it < 16; ++it) {
        const int kv0 = it * 64;
        // own stage-t loads landed (4 newest = stage t+1 stay in flight)
        if (it == 15) asm volatile("s_waitcnt vmcnt(0)" ::: "memory");
        else          asm volatile("s_waitcnt vmcnt(4)" ::: "memory");
        __builtin_amdgcn_s_barrier();                // all waves landed stage t
        asm volatile("" ::: "memory");
        // prefetch next iter's sw (BEFORE next stage: stays older in vmcnt order)
        const int kvn = (it < 15) ? kv0 + 64 : kv0;
        float4 swn[4];
#pragma unroll
        for (int j = 0; j < 4; j++) swn[j] = *(const float4*)(swrow + kvn + j * 16 + 4 * g);
        if (it < 14) STAGE((it + 2) % 3, kv0 + 128);

        const char* kB = (const char*)kbuf[it % 3];
        const char* vB = (const char*)vbuf[it % 3];
#pragma unroll
        for (int ks2 = 0; ks2 < 2; ++ks2) {
            s16x8 kc0 = *(const s16x8*)(kB + ((ks2 * 32 + c) << 7) + (((0 + g) ^ swz) << 4));
            s16x8 kc1 = *(const s16x8*)(kB + ((ks2 * 32 + c) << 7) + (((4 + g) ^ swz) << 4));
            s16x8 kc2 = *(const s16x8*)(kB + ((ks2 * 32 + 16 + c) << 7) + (((0 + g) ^ swz) << 4));
            s16x8 kc3 = *(const s16x8*)(kB + ((ks2 * 32 + 16 + c) << 7) + (((4 + g) ^ swz) << 4));

            __builtin_amdgcn_s_setprio(1);
            f32x4 ss0 = {0.f, 0.f, 0.f, 0.f}, ss1 = {0.f, 0.f, 0.f, 0.f};
            ss0 = mfma16(kc0, qf0, ss0); ss0 = mfma16(kc1, qf1, ss0);
            ss1 = mfma16(kc2, qf0, ss1); ss1 = mfma16(kc3, qf1, ss1);
            __builtin_amdgcn_s_setprio(0);

            float4 swa = swc[2 * ks2], swb = swc[2 * ks2 + 1];
            float z0[4], z1[4];
#pragma unroll
            for (int r = 0; r < 4; r++) {
                z0[r] = ss0[r] * SC + (&swa.x)[r] * L2E;
                z1[r] = ss1[r] * SC + (&swb.x)[r] * L2E;
            }
            float tm = fmaxf(fmaxf(fmaxf(z0[0], z0[1]), fmaxf(z0[2], z0[3])),
                             fmaxf(fmaxf(z1[0], z1[1]), fmaxf(z1[2], z1[3])));
            tm = fmaxf(tm, __shfl_xor(tm, 16, 64));
            tm = fmaxf(tm, __shfl_xor(tm, 32, 64));

            const bool need = __any((int)(tm > mr + 8.0f));
            float mn = mr, f = 1.0f;
            if (need) { mn = fmaxf(mr, tm); f = __builtin_amdgcn_exp2f(mr - mn); }

            float p0[4], p1[4];
#pragma unroll
            for (int r = 0; r < 4; r++) {
                p0[r] = __builtin_amdgcn_exp2f(z0[r] - mn);
                p1[r] = __builtin_amdgcn_exp2f(z1[r] - mn);
            }
            float rs = (p0[0] + p0[1]) + (p0[2] + p0[3]) + (p1[0] + p1[1]) + (p1[2] + p1[3]);
            rs += __shfl_xor(rs, 16, 64);
            rs += __shfl_xor(rs, 32, 64);

            if (need) {
                mr = mn;
                lr = lr * f + rs;
#pragma unroll
                for (int nf = 0; nf < 4; nf++)
#pragma unroll
                    for (int r = 0; r < 4; r++) acc[nf][r] *= f;
            } else {
                lr += rs;
            }

            u16x4 w0, w1;
#pragma unroll
            for (int r = 0; r < 4; r++) { w0[r] = f2bf(p0[r]); w1[r] = f2bf(p1[r]); }
            *(u16x4*)(wp + c * 40 + 4 * g) = w0;
            *(u16x4*)(wp + c * 40 + 16 + 4 * g) = w1;
            s16x8 ap = *(const s16x8*)((const char*)wp + c * 80 + g * 16);

            __builtin_amdgcn_s_setprio(1);
#pragma unroll
            for (int nf = 0; nf < 4; nf++) {
                s16x8 vf = *(const s16x8*)(vB + ((nf * 16 + c) << 7) + ((((ks2 << 2) + g) ^ swz) << 4));
                acc[nf] = mfma16(vf, ap, acc[nf]);       // ctx^T += V^T . P^T
            }
            __builtin_amdgcn_s_setprio(0);
        }
#pragma unroll
        for (int j = 0; j < 4; j++) swc[j] = swn[j];
    }
#undef STAGE

    // epilogue: normalize (lane-local), transpose ctx^T -> ctx via LDS scratch
    float inv = 1.0f / lr;
#pragma unroll
    for (int nf = 0; nf < 4; nf++)
#pragma unroll
        for (int r = 0; r < 4; r++) acc[nf][r] *= inv;

    __syncthreads();                                  // staging bufs now dead
    float* scr = (float*)kbuf + wave * 1088;          // 64 x 17 f32 per wave
#pragma unroll
    for (int nf = 0; nf < 4; nf++)
#pragma unroll
        for (int r = 0; r < 4; r++)
            scr[(nf * 16 + 4 * g + r) * 17 + c] = acc[nf][r];
    __syncthreads();
    u16x8 o0, o1;
#pragma unroll
    for (int j = 0; j < 8; j++) o0[j] = f2bf(scr[(g * 16 + j) * 17 + c]);
#pragma unroll
    for (int j = 0; j < 8; j++) o1[j] = f2bf(scr[(g * 16 + 8 + j) * 17 + c]);
    unsigned short* dst = ctx + ((size_t)(b_ << 10) + qr + c) * 1024 + (h << 6) + g * 16;
    *(u16x8*)dst = o0;
    *(u16x8*)(dst + 8) = o1;
}

// ------------------------------- launch ------------------------------------
extern "C" void kernel_launch(void* const* d_in, const int* in_sizes, int n_in,
                              void* d_out, int out_size, void* d_ws, size_t ws_size,
                              hipStream_t stream) {
    const float* x    = (const float*)d_in[0];
    const float* sb   = (const float*)d_in[1];
    const float* Wqkv = (const float*)d_in[2];
    const float* bqkv = (const float*)d_in[3];
    const float* Ws   = (const float*)d_in[4];
    const float* bs   = (const float*)d_in[5];
    const float* Wo   = (const float*)d_in[6];
    const float* bo   = (const float*)d_in[7];
    float* out = (float*)d_out;

    char* ws = (char*)d_ws;
    unsigned short* xb    = (unsigned short*)(ws);
    unsigned short* sbb   = (unsigned short*)(ws + ((size_t)4 << 20));
    unsigned short* wqkvt = (unsigned short*)(ws + ((size_t)8 << 20));
    unsigned short* wst   = (unsigned short*)(ws + ((size_t)14 << 20));
    unsigned short* wot   = (unsigned short*)(ws + ((size_t)16 << 20));
    unsigned short* qb    = (unsigned short*)(ws + ((size_t)18 << 20));
    unsigned short* kb    = (unsigned short*)(ws + ((size_t)22 << 20));
    unsigned short* vtb   = (unsigned short*)(ws + ((size_t)26 << 20));
    float*          swf   = (float*)        (ws + ((size_t)30 << 20));
    unsigned short* ctxb  = (unsigned short*)(ws + ((size_t)38 << 20));

    prep_k<<<dim3(3328), dim3(256), 0, stream>>>(x, sb, Wqkv, Ws, Wo,
                                                 xb, sbb, wqkvt, wst, wot);
    gemm01_k<<<dim3(32, 32), dim3(256), 0, stream>>>(xb, wqkvt, bqkv, sbb, wst, bs,
                                                     qb, kb, vtb, swf);
    attn_k<<<dim3(512), dim3(256), 0, stream>>>(qb, kb, vtb, swf, ctxb);
    gemmo_k<<<dim3(8, 32), dim3(256), 0, stream>>>(ctxb, wot, bo, out);
}

// Round 7
// 85.930 us; speedup vs baseline: 1.1065x; 1.1065x over previous
//
#include <hip/hip_runtime.h>
#include <stdint.h>
#include <stddef.h>

// ---------------------------------------------------------------------------
// StructureAwareAttention  (B=2, L=1024, D=1024, H=16, HD=64)
//   prep: cvt x,sb -> bf16; transpose Wqkv/Ws/Wo -> [N][K] bf16   (1 kernel)
//   gemm01 (merged, 128x128 BK=64 dbuf, 512 blocks = 2/CU exact):
//       qkv = x@Wqkv+bqkv -> q,k [B,H,L,64] bf16, v^T [B,H,64,L] bf16
//       sw  = sb@Ws+bs -> f32 [B,L,L]
//   attn: flash (R5 structure), swapped QK^T + swapped PV, K/V LDS-staged
//       2-buf, XOR-swizzled both sides, KVBLK=64, defer-max, setprio,
//       row-sum via ones-MFMA (l is an extra accumulator row)
//   out = ctx@Wo + bo -> f32   (64x128 BK=64 dbuf, 256 blocks = 1/CU)
// Workspace:
//   0: xb 4MB | 4MB: sbb 4MB | 8MB: Wqkv^T 6MB | 14MB: Ws^T 2MB | 16MB: Wo^T 2MB
//   18MB: q 4MB | 22MB: k 4MB | 26MB: v^T 4MB | 30MB: sw(f32) 8MB | 38MB: ctx 4MB
// ---------------------------------------------------------------------------

typedef float f32x4 __attribute__((ext_vector_type(4)));
typedef short s16x8 __attribute__((ext_vector_type(8)));
typedef unsigned short u16x8 __attribute__((ext_vector_type(8)));
typedef unsigned short u16x4 __attribute__((ext_vector_type(4)));

__device__ inline unsigned short f2bf(float f) {          // RNE f32 -> bf16
    unsigned u = __builtin_bit_cast(unsigned, f);
    u += 0x7fffu + ((u >> 16) & 1u);
    return (unsigned short)(u >> 16);
}

__device__ inline f32x4 mfma16(s16x8 a, s16x8 b, f32x4 c) {
    return __builtin_amdgcn_mfma_f32_16x16x32_bf16(a, b, c, 0, 0, 0);
}

__device__ inline void gld_lds16(const void* g, const void* lds_base) {
    __builtin_amdgcn_global_load_lds(
        (const __attribute__((address_space(1))) void*)(uintptr_t)g,
        (__attribute__((address_space(3))) void*)(unsigned)(uintptr_t)lds_base,
        16, 0, 0);
}

// ------------------------------ prep ---------------------------------------
// blocks [0,1024): cvt x | [1024,2048): cvt sb | [2048,2816): Wqkv^T
// [2816,3072): Ws^T | [3072,3328): Wo^T
__global__ __launch_bounds__(256) void prep_k(const float* __restrict__ x,
                                              const float* __restrict__ sb,
                                              const float* __restrict__ Wqkv,
                                              const float* __restrict__ Ws,
                                              const float* __restrict__ Wo,
                                              unsigned short* __restrict__ xb,
                                              unsigned short* __restrict__ sbb,
                                              unsigned short* __restrict__ wqkvt,
                                              unsigned short* __restrict__ wst,
                                              unsigned short* __restrict__ wot) {
    __shared__ float tile[64][65];
    const int blk = blockIdx.x, t = threadIdx.x;
    if (blk < 2048) {                                   // bf16 convert, 8 elem/thread
        const float* src = (blk < 1024) ? x : sb;
        unsigned short* dst = (blk < 1024) ? xb : sbb;
        int i = (blk & 1023) * 256 + t;
        const float4* s4 = (const float4*)src;
        float4 a = s4[2 * i], b = s4[2 * i + 1];
        u16x8 o;
        o[0] = f2bf(a.x); o[1] = f2bf(a.y); o[2] = f2bf(a.z); o[3] = f2bf(a.w);
        o[4] = f2bf(b.x); o[5] = f2bf(b.y); o[6] = f2bf(b.z); o[7] = f2bf(b.w);
        *(u16x8*)(dst + (size_t)i * 8) = o;
        return;
    }
    int tt = blk - 2048;
    const float* W; unsigned short* Wt; int N, n0, k0;
    if (tt < 768)       { W = Wqkv; Wt = wqkvt; N = 3072; n0 = (tt % 48) * 64; k0 = (tt / 48) * 64; }
    else if (tt < 1024) { tt -= 768;  W = Ws; Wt = wst; N = 1024; n0 = (tt & 15) * 64; k0 = (tt >> 4) * 64; }
    else                { tt -= 1024; W = Wo; Wt = wot; N = 1024; n0 = (tt & 15) * 64; k0 = (tt >> 4) * 64; }
    const int lr = t >> 4, lc = (t & 15) * 4;
#pragma unroll
    for (int rr = 0; rr < 4; rr++) {
        int r = lr + rr * 16;
        float4 v = *(const float4*)(W + (size_t)(k0 + r) * N + n0 + lc);
        tile[r][lc] = v.x; tile[r][lc + 1] = v.y; tile[r][lc + 2] = v.z; tile[r][lc + 3] = v.w;
    }
    __syncthreads();
    const int wn = t >> 3, wk = (t & 7) * 8;
#pragma unroll
    for (int rr = 0; rr < 2; rr++) {
        int n = wn + rr * 32;
        u16x8 o;
#pragma unroll
        for (int j = 0; j < 8; j++) o[j] = f2bf(tile[wk + j][n]);
        *(u16x8*)(Wt + (size_t)(n0 + n) * 1024 + k0 + wk) = o;
    }
}

// ---------------------- merged 128x128 GEMM (qkv + sw) ----------------------
// C[M,N] = A[M,1024]@Bt[N,1024]^T + bias. 128x128 tile, BK=64, 4 waves
// (each wave a 64x64 quadrant: MI=NI=4 -> 0.5 ds_read per MFMA), 2-phase
// double-buffered LDS (64KB), 1 barrier/K-step.
// epi 0: scatter bf16 q/k [B,H,L,64], v^T [B,H,64,L];  epi 1: f32 [M][1024].
__global__ __launch_bounds__(256, 2) void gemm01_k(const unsigned short* __restrict__ xb,
                                                   const unsigned short* __restrict__ wqkvt,
                                                   const float* __restrict__ bqkv,
                                                   const unsigned short* __restrict__ sbb,
                                                   const unsigned short* __restrict__ wst,
                                                   const float* __restrict__ bs,
                                                   unsigned short* __restrict__ q,
                                                   unsigned short* __restrict__ kk_,
                                                   unsigned short* __restrict__ vt,
                                                   float* __restrict__ swf) {
    __shared__ unsigned short lA[2][8192];   // [128 m][64 k] per buf
    __shared__ unsigned short lB[2][8192];   // [128 n][64 k] per buf
    const int blk = blockIdx.x, t = threadIdx.x;
    const int wave = t >> 6, lane = t & 63, c = lane & 15, g = lane >> 4;
    const int wr = (wave >> 1) * 64, wc = (wave & 1) * 64;

    const unsigned short* A;
    const unsigned short* Bt;
    const float* bias;
    int bn0, bm0, epi;
    if (blk < 384) { A = xb;  Bt = wqkvt; bias = bqkv; epi = 0;
                     bn0 = (blk % 24) * 128; bm0 = (blk / 24) * 128; }
    else           { int bb = blk - 384; A = sbb; Bt = wst; bias = bs; epi = 1;
                     bn0 = (bb & 7) * 128; bm0 = (bb >> 3) * 128; }

    // staging: 1024 16B-slots per matrix per buf; slot s: row=s>>3,
    // phys chunk s&7 holds logical chunk (s&7)^(row&7)
    size_t aoff[4], boff[4];
#pragma unroll
    for (int j = 0; j < 4; j++) {
        int s = j * 256 + t, row = s >> 3, ch = (s & 7) ^ (row & 7);
        aoff[j] = (size_t)(bm0 + row) * 1024 + ch * 8;
        boff[j] = (size_t)(bn0 + row) * 1024 + ch * 8;
    }
    char* lAb0 = (char*)lA[0]; char* lBb0 = (char*)lB[0];

#define GS128(buf, kt)                                                                    \
    do {                                                                                  \
        _Pragma("unroll")                                                                 \
        for (int j = 0; j < 4; j++)                                                       \
            gld_lds16(A + aoff[j] + (kt), lAb0 + (buf) * 16384 + j * 4096 + wave * 1024); \
        _Pragma("unroll")                                                                 \
        for (int j = 0; j < 4; j++)                                                       \
            gld_lds16(Bt + boff[j] + (kt), lBb0 + (buf) * 16384 + j * 4096 + wave * 1024);\
    } while (0)

    f32x4 acc[4][4];
#pragma unroll
    for (int i = 0; i < 4; i++)
#pragma unroll
        for (int j = 0; j < 4; j++) acc[i][j] = {0.f, 0.f, 0.f, 0.f};

    GS128(0, 0);
    for (int ks = 0; ks < 16; ++ks) {
        __syncthreads();                              // stage of buf ks&1 landed
        if (ks < 15) GS128((ks + 1) & 1, (ks + 1) * 64);
        const char* aB = lAb0 + (ks & 1) * 16384;
        const char* bB = lBb0 + (ks & 1) * 16384;
#pragma unroll
        for (int kk2 = 0; kk2 < 2; ++kk2) {
            s16x8 af[4], bfr[4];
#pragma unroll
            for (int i = 0; i < 4; i++) {
                int r_ = wr + i * 16 + c;
                af[i] = *(const s16x8*)(aB + r_ * 128 + (((kk2 * 4 + g) ^ (r_ & 7)) << 4));
            }
#pragma unroll
            for (int j = 0; j < 4; j++) {
                int r_ = wc + j * 16 + c;
                bfr[j] = *(const s16x8*)(bB + r_ * 128 + (((kk2 * 4 + g) ^ (r_ & 7)) << 4));
            }
            __builtin_amdgcn_s_setprio(1);
#pragma unroll
            for (int i = 0; i < 4; i++)
#pragma unroll
                for (int j = 0; j < 4; j++)
                    acc[i][j] = mfma16(af[i], bfr[j], acc[i][j]);
            __builtin_amdgcn_s_setprio(0);
        }
    }
#undef GS128

#pragma unroll
    for (int i = 0; i < 4; i++) {
#pragma unroll
        for (int j = 0; j < 4; j++) {
            const int n = bn0 + wc + j * 16 + c;
            const float bv = bias[n];
#pragma unroll
            for (int r = 0; r < 4; r++) {
                const int m = bm0 + wr + i * 16 + g * 4 + r;
                float v = acc[i][j][r] + bv;
                if (epi == 0) {
                    const int sel = n >> 10, h = (n >> 6) & 15, d = n & 63;
                    const int b_ = m >> 10, l_ = m & 1023;
                    const size_t bh = (size_t)((b_ << 4) + h);
                    unsigned short hv = f2bf(v);
                    if (sel == 0)      q[(bh * 1024 + l_) * 64 + d] = hv;
                    else if (sel == 1) kk_[(bh * 1024 + l_) * 64 + d] = hv;
                    else               vt[(bh * 64 + d) * 1024 + l_] = hv;
                } else {
                    swf[(size_t)m * 1024 + n] = v;
                }
            }
        }
    }
}

// ---------------------------- out GEMM (64x128) -----------------------------
// out = ctx@Wo^T + bo, f32. 64x128 tile, BK=64, dbuf, 256 blocks = 1/CU.
__global__ __launch_bounds__(256, 3) void gemmo_k(const unsigned short* __restrict__ A,
                                                  const unsigned short* __restrict__ Bt,
                                                  const float* __restrict__ bias,
                                                  float* __restrict__ outf) {
    __shared__ unsigned short lA[2][4096];
    __shared__ unsigned short lB[2][8192];
    const int t = threadIdx.x;
    const int wave = t >> 6, lane = t & 63, c = lane & 15, g = lane >> 4;
    const int bn0 = blockIdx.x * 128, bm0 = blockIdx.y * 64;
    const int wc = wave * 32;

    size_t aoff[2], boff[4];
#pragma unroll
    for (int j = 0; j < 2; j++) {
        int s = j * 256 + t, row = s >> 3, ch = (s & 7) ^ (row & 7);
        aoff[j] = (size_t)(bm0 + row) * 1024 + ch * 8;
    }
#pragma unroll
    for (int j = 0; j < 4; j++) {
        int s = j * 256 + t, row = s >> 3, ch = (s & 7) ^ (row & 7);
        boff[j] = (size_t)(bn0 + row) * 1024 + ch * 8;
    }
    char* lAb0 = (char*)lA[0]; char* lBb0 = (char*)lB[0];

#define GSTAGE(buf, kt)                                                                  \
    do {                                                                                 \
        _Pragma("unroll")                                                                \
        for (int j = 0; j < 2; j++)                                                      \
            gld_lds16(A + aoff[j] + (kt), lAb0 + (buf) * 8192 + j * 4096 + wave * 1024); \
        _Pragma("unroll")                                                                \
        for (int j = 0; j < 4; j++)                                                      \
            gld_lds16(Bt + boff[j] + (kt), lBb0 + (buf) * 16384 + j * 4096 + wave * 1024);\
    } while (0)

    f32x4 acc[4][2];
#pragma unroll
    for (int i = 0; i < 4; i++)
#pragma unroll
        for (int j = 0; j < 2; j++) acc[i][j] = {0.f, 0.f, 0.f, 0.f};

    GSTAGE(0, 0);
    for (int ks = 0; ks < 16; ++ks) {
        __syncthreads();
        if (ks < 15) GSTAGE((ks + 1) & 1, (ks + 1) * 64);
        const char* aB = lAb0 + (ks & 1) * 8192;
        const char* bB = lBb0 + (ks & 1) * 16384;
#pragma unroll
        for (int kk2 = 0; kk2 < 2; ++kk2) {
            s16x8 af[4], bfr[2];
#pragma unroll
            for (int i = 0; i < 4; i++) {
                int r_ = i * 16 + c;
                af[i] = *(const s16x8*)(aB + r_ * 128 + (((kk2 * 4 + g) ^ (r_ & 7)) << 4));
            }
#pragma unroll
            for (int j = 0; j < 2; j++) {
                int r_ = wc + j * 16 + c;
                bfr[j] = *(const s16x8*)(bB + r_ * 128 + (((kk2 * 4 + g) ^ (r_ & 7)) << 4));
            }
            __builtin_amdgcn_s_setprio(1);
#pragma unroll
            for (int i = 0; i < 4; i++)
#pragma unroll
                for (int j = 0; j < 2; j++)
                    acc[i][j] = mfma16(af[i], bfr[j], acc[i][j]);
            __builtin_amdgcn_s_setprio(0);
        }
    }
#undef GSTAGE

#pragma unroll
    for (int i = 0; i < 4; i++) {
#pragma unroll
        for (int j = 0; j < 2; j++) {
            const int n = bn0 + wc + j * 16 + c;
            const float bv = bias[n];
#pragma unroll
            for (int r = 0; r < 4; r++) {
                const int m = bm0 + i * 16 + g * 4 + r;
                outf[(size_t)m * 1024 + n] = acc[i][j][r] + bv;
            }
        }
    }
}

// ------------------------------ attention ----------------------------------
// R5 structure: grid 512, wave = 16 q-rows, KVBLK=64, 2-buf LDS staging
// (swizzled both sides), swapped QK^T + swapped PV (lane-local state),
// defer-max THR=8, setprio on MFMA. Row-sum via ones-MFMA: l is one more
// accumulator row (removes sum shfl-reduce; denominator consistent with
// bf16 PV numerator).
__global__ __launch_bounds__(256, 2) void attn_k(const unsigned short* __restrict__ q,
                                                 const unsigned short* __restrict__ k,
                                                 const unsigned short* __restrict__ vt,
                                                 const float* __restrict__ sw,
                                                 unsigned short* __restrict__ ctx) {
    __shared__ unsigned short kbuf[2][4096];         // [64 kv][64 hd] swizzled
    __shared__ unsigned short vbuf[2][4096];         // [64 d][64 kv] swizzled
    __shared__ unsigned short lP[4][640];            // per wave: 16 q-rows x 40 (pad)
    const int t = threadIdx.x, wave = t >> 6, lane = t & 63, c = lane & 15, g = lane >> 4;
    const int blk = blockIdx.x;
    const int qt = blk & 15, bh = blk >> 4, b_ = bh >> 4, h = bh & 15;
    const int qr = qt * 64 + wave * 16;

    const unsigned short* qbase = q + ((size_t)bh * 1024 + qr) * 64;
    s16x8 qf0 = *(const s16x8*)(qbase + (size_t)c * 64 + g * 8);
    s16x8 qf1 = *(const s16x8*)(qbase + (size_t)c * 64 + 32 + g * 8);

    const unsigned short* kg = k + (size_t)bh * 65536;     // [1024][64]
    const unsigned short* vg = vt + (size_t)bh * 65536;    // [64][1024]
    const float* swrow = sw + ((size_t)b_ * 1024 + qr + c) * 1024;

    const int s0 = wave * 128 + lane, s1 = s0 + 64;
    const int r0 = s0 >> 3, ch0 = (s0 & 7) ^ (r0 & 7);
    const int r1 = s1 >> 3, ch1 = (s1 & 7) ^ (r1 & 7);

    const float SC  = 0.125f * 1.4426950408889634f;
    const float L2E = 1.4426950408889634f;

    const short one_bf = (short)0x3F80;              // bf16 1.0
    const s16x8 ones = { one_bf, one_bf, one_bf, one_bf, one_bf, one_bf, one_bf, one_bf };

    float mr = -1e30f;               // running max for q-row c (replicated over g)
    f32x4 acc[4];                    // acc[nf][r] = ctx^T[d = nf*16+4g+r][q = c]
    f32x4 accl = {0.f, 0.f, 0.f, 0.f};   // accl[*] = running sum l for q-row c
#pragma unroll
    for (int nf = 0; nf < 4; nf++) acc[nf] = {0.f, 0.f, 0.f, 0.f};
    unsigned short* wp = lP[wave];
    const int swz = (c & 7);

#define STAGE(buf, kv0)                                                                     \
    do {                                                                                    \
        gld_lds16(kg + (size_t)((kv0) + r0) * 64 + ch0 * 8, (char*)kbuf[buf] + wave * 2048);            \
        gld_lds16(kg + (size_t)((kv0) + r1) * 64 + ch1 * 8, (char*)kbuf[buf] + wave * 2048 + 1024);     \
        gld_lds16(vg + (size_t)r0 * 1024 + (kv0) + ch0 * 8, (char*)vbuf[buf] + wave * 2048);            \
        gld_lds16(vg + (size_t)r1 * 1024 + (kv0) + ch1 * 8, (char*)vbuf[buf] + wave * 2048 + 1024);     \
    } while (0)

    STAGE(0, 0);
    __syncthreads();

    int cur = 0;
    for (int it = 0; it < 16; ++it) {
        const int kv0 = it * 64;
        if (it < 15) STAGE(cur ^ 1, kv0 + 64);
        float4 sws[4];
#pragma unroll
        for (int j = 0; j < 4; j++) sws[j] = *(const float4*)(swrow + kv0 + j * 16 + 4 * g);

        const char* kB = (const char*)kbuf[cur];
        const char* vB = (const char*)vbuf[cur];
#pragma unroll
        for (int ks2 = 0; ks2 < 2; ++ks2) {
            s16x8 kc0 = *(const s16x8*)(kB + ((ks2 * 32 + c) << 7) + (((0 + g) ^ swz) << 4));
            s16x8 kc1 = *(const s16x8*)(kB + ((ks2 * 32 + c) << 7) + (((4 + g) ^ swz) << 4));
            s16x8 kc2 = *(const s16x8*)(kB + ((ks2 * 32 + 16 + c) << 7) + (((0 + g) ^ swz) << 4));
            s16x8 kc3 = *(const s16x8*)(kB + ((ks2 * 32 + 16 + c) << 7) + (((4 + g) ^ swz) << 4));

            __builtin_amdgcn_s_setprio(1);
            f32x4 ss0 = {0.f, 0.f, 0.f, 0.f}, ss1 = {0.f, 0.f, 0.f, 0.f};
            ss0 = mfma16(kc0, qf0, ss0); ss0 = mfma16(kc1, qf1, ss0);
            ss1 = mfma16(kc2, qf0, ss1); ss1 = mfma16(kc3, qf1, ss1);
            __builtin_amdgcn_s_setprio(0);

            float4 swa = sws[2 * ks2], swb = sws[2 * ks2 + 1];
            float z0[4], z1[4];
#pragma unroll
            for (int r = 0; r < 4; r++) {
                z0[r] = ss0[r] * SC + (&swa.x)[r] * L2E;
                z1[r] = ss1[r] * SC + (&swb.x)[r] * L2E;
            }
            float tm = fmaxf(fmaxf(fmaxf(z0[0], z0[1]), fmaxf(z0[2], z0[3])),
                             fmaxf(fmaxf(z1[0], z1[1]), fmaxf(z1[2], z1[3])));
            tm = fmaxf(tm, __shfl_xor(tm, 16, 64));
            tm = fmaxf(tm, __shfl_xor(tm, 32, 64));

            // defer-max: only rescale when tile max exceeds budget (THR=8 bits)
            const bool need = __any((int)(tm > mr + 8.0f));
            float mn = mr;
            if (need) {
                mn = fmaxf(mr, tm);
                float f = __builtin_amdgcn_exp2f(mr - mn);
                mr = mn;
                accl *= f;
#pragma unroll
                for (int nf = 0; nf < 4; nf++)
#pragma unroll
                    for (int r = 0; r < 4; r++) acc[nf][r] *= f;
            }

            float p0[4], p1[4];
#pragma unroll
            for (int r = 0; r < 4; r++) {
                p0[r] = __builtin_amdgcn_exp2f(z0[r] - mn);
                p1[r] = __builtin_amdgcn_exp2f(z1[r] - mn);
            }

            // P -> LDS transpose: lane owns (q=c, k=4g..4g+3) and (q=c, k=16+4g..)
            u16x4 w0, w1;
#pragma unroll
            for (int r = 0; r < 4; r++) { w0[r] = f2bf(p0[r]); w1[r] = f2bf(p1[r]); }
            *(u16x4*)(wp + c * 40 + 4 * g) = w0;
            *(u16x4*)(wp + c * 40 + 16 + 4 * g) = w1;
            s16x8 ap = *(const s16x8*)((const char*)wp + c * 80 + g * 16);

            __builtin_amdgcn_s_setprio(1);
            accl = mfma16(ones, ap, accl);               // l += row-sum of P
#pragma unroll
            for (int nf = 0; nf < 4; nf++) {
                s16x8 vf = *(const s16x8*)(vB + ((nf * 16 + c) << 7) + ((((ks2 << 2) + g) ^ swz) << 4));
                acc[nf] = mfma16(vf, ap, acc[nf]);       // ctx^T += V^T . P^T
            }
            __builtin_amdgcn_s_setprio(0);
        }
        __syncthreads();
        cur ^= 1;
    }
#undef STAGE

    // epilogue: normalize (lane-local), transpose ctx^T -> ctx via LDS scratch
    float inv = 1.0f / accl[0];
#pragma unroll
    for (int nf = 0; nf < 4; nf++)
#pragma unroll
        for (int r = 0; r < 4; r++) acc[nf][r] *= inv;

    __syncthreads();                                  // staging bufs now dead
    float* scr = (wave < 2) ? ((float*)kbuf + wave * 1088)
                            : ((float*)vbuf + (wave - 2) * 1088);   // 64 x 17 f32
#pragma unroll
    for (int nf = 0; nf < 4; nf++)
#pragma unroll
        for (int r = 0; r < 4; r++)
            scr[(nf * 16 + 4 * g + r) * 17 + c] = acc[nf][r];
    __syncthreads();
    u16x8 o0, o1;
#pragma unroll
    for (int j = 0; j < 8; j++) o0[j] = f2bf(scr[(g * 16 + j) * 17 + c]);
#pragma unroll
    for (int j = 0; j < 8; j++) o1[j] = f2bf(scr[(g * 16 + 8 + j) * 17 + c]);
    unsigned short* dst = ctx + ((size_t)(b_ << 10) + qr + c) * 1024 + (h << 6) + g * 16;
    *(u16x8*)dst = o0;
    *(u16x8*)(dst + 8) = o1;
}

// ------------------------------- launch ------------------------------------
extern "C" void kernel_launch(void* const* d_in, const int* in_sizes, int n_in,
                              void* d_out, int out_size, void* d_ws, size_t ws_size,
                              hipStream_t stream) {
    const float* x    = (const float*)d_in[0];
    const float* sb   = (const float*)d_in[1];
    const float* Wqkv = (const float*)d_in[2];
    const float* bqkv = (const float*)d_in[3];
    const float* Ws   = (const float*)d_in[4];
    const float* bs   = (const float*)d_in[5];
    const float* Wo   = (const float*)d_in[6];
    const float* bo   = (const float*)d_in[7];
    float* out = (float*)d_out;

    char* ws = (char*)d_ws;
    unsigned short* xb    = (unsigned short*)(ws);
    unsigned short* sbb   = (unsigned short*)(ws + ((size_t)4 << 20));
    unsigned short* wqkvt = (unsigned short*)(ws + ((size_t)8 << 20));
    unsigned short* wst   = (unsigned short*)(ws + ((size_t)14 << 20));
    unsigned short* wot   = (unsigned short*)(ws + ((size_t)16 << 20));
    unsigned short* qb    = (unsigned short*)(ws + ((size_t)18 << 20));
    unsigned short* kb    = (unsigned short*)(ws + ((size_t)22 << 20));
    unsigned short* vtb   = (unsigned short*)(ws + ((size_t)26 << 20));
    float*          swf   = (float*)        (ws + ((size_t)30 << 20));
    unsigned short* ctxb  = (unsigned short*)(ws + ((size_t)38 << 20));

    prep_k<<<dim3(3328), dim3(256), 0, stream>>>(x, sb, Wqkv, Ws, Wo,
                                                 xb, sbb, wqkvt, wst, wot);
    gemm01_k<<<dim3(512), dim3(256), 0, stream>>>(xb, wqkvt, bqkv, sbb, wst, bs,
                                                  qb, kb, vtb, swf);
    attn_k<<<dim3(512), dim3(256), 0, stream>>>(qb, kb, vtb, swf, ctxb);
    gemmo_k<<<dim3(8, 32), dim3(256), 0, stream>>>(ctxb, wot, bo, out);
}

// Round 8
// 83.706 us; speedup vs baseline: 1.1359x; 1.0266x over previous
//
#include <hip/hip_runtime.h>
#include <stdint.h>
#include <stddef.h>

// ---------------------------------------------------------------------------
// StructureAwareAttention  (B=2, L=1024, D=1024, H=16, HD=64)
//   prep: cvt x,sb -> bf16; transpose Wqkv/Ws/Wo -> [N][K] bf16   (1 kernel)
//   gemm01 (merged, 128x128 BK=64 dbuf, 512 blocks = 2/CU exact):
//       qkv = x@Wqkv+bqkv -> q,k [B,H,L,64] bf16, v^T [B,H,64,L] bf16
//       sw  = sb@Ws+bs -> f32 [B,L,L]
//   attn: flash, swapped QK^T + swapped PV, K/V LDS-staged 2-buf XOR-swizzled,
//       KVBLK=64, STATIC-MAX softmax (P = exp2(z-16), shift-invariant & exact
//       pow2 scaling -> no max tracking, no shuffles), l via ones-MFMA
//   out = ctx@Wo + bo -> f32   (64x128 BK=64 dbuf, 256 blocks = 1/CU)
// Workspace:
//   0: xb 4MB | 4MB: sbb 4MB | 8MB: Wqkv^T 6MB | 14MB: Ws^T 2MB | 16MB: Wo^T 2MB
//   18MB: q 4MB | 22MB: k 4MB | 26MB: v^T 4MB | 30MB: sw(f32) 8MB | 38MB: ctx 4MB
// ---------------------------------------------------------------------------

typedef float f32x4 __attribute__((ext_vector_type(4)));
typedef short s16x8 __attribute__((ext_vector_type(8)));
typedef unsigned short u16x8 __attribute__((ext_vector_type(8)));
typedef unsigned short u16x4 __attribute__((ext_vector_type(4)));

__device__ inline unsigned short f2bf(float f) {          // RNE f32 -> bf16
    unsigned u = __builtin_bit_cast(unsigned, f);
    u += 0x7fffu + ((u >> 16) & 1u);
    return (unsigned short)(u >> 16);
}

__device__ inline f32x4 mfma16(s16x8 a, s16x8 b, f32x4 c) {
    return __builtin_amdgcn_mfma_f32_16x16x32_bf16(a, b, c, 0, 0, 0);
}

__device__ inline void gld_lds16(const void* g, const void* lds_base) {
    __builtin_amdgcn_global_load_lds(
        (const __attribute__((address_space(1))) void*)(uintptr_t)g,
        (__attribute__((address_space(3))) void*)(unsigned)(uintptr_t)lds_base,
        16, 0, 0);
}

// ------------------------------ prep ---------------------------------------
__global__ __launch_bounds__(256) void prep_k(const float* __restrict__ x,
                                              const float* __restrict__ sb,
                                              const float* __restrict__ Wqkv,
                                              const float* __restrict__ Ws,
                                              const float* __restrict__ Wo,
                                              unsigned short* __restrict__ xb,
                                              unsigned short* __restrict__ sbb,
                                              unsigned short* __restrict__ wqkvt,
                                              unsigned short* __restrict__ wst,
                                              unsigned short* __restrict__ wot) {
    __shared__ float tile[64][65];
    const int blk = blockIdx.x, t = threadIdx.x;
    if (blk < 2048) {
        const float* src = (blk < 1024) ? x : sb;
        unsigned short* dst = (blk < 1024) ? xb : sbb;
        int i = (blk & 1023) * 256 + t;
        const float4* s4 = (const float4*)src;
        float4 a = s4[2 * i], b = s4[2 * i + 1];
        u16x8 o;
        o[0] = f2bf(a.x); o[1] = f2bf(a.y); o[2] = f2bf(a.z); o[3] = f2bf(a.w);
        o[4] = f2bf(b.x); o[5] = f2bf(b.y); o[6] = f2bf(b.z); o[7] = f2bf(b.w);
        *(u16x8*)(dst + (size_t)i * 8) = o;
        return;
    }
    int tt = blk - 2048;
    const float* W; unsigned short* Wt; int N, n0, k0;
    if (tt < 768)       { W = Wqkv; Wt = wqkvt; N = 3072; n0 = (tt % 48) * 64; k0 = (tt / 48) * 64; }
    else if (tt < 1024) { tt -= 768;  W = Ws; Wt = wst; N = 1024; n0 = (tt & 15) * 64; k0 = (tt >> 4) * 64; }
    else                { tt -= 1024; W = Wo; Wt = wot; N = 1024; n0 = (tt & 15) * 64; k0 = (tt >> 4) * 64; }
    const int lr = t >> 4, lc = (t & 15) * 4;
#pragma unroll
    for (int rr = 0; rr < 4; rr++) {
        int r = lr + rr * 16;
        float4 v = *(const float4*)(W + (size_t)(k0 + r) * N + n0 + lc);
        tile[r][lc] = v.x; tile[r][lc + 1] = v.y; tile[r][lc + 2] = v.z; tile[r][lc + 3] = v.w;
    }
    __syncthreads();
    const int wn = t >> 3, wk = (t & 7) * 8;
#pragma unroll
    for (int rr = 0; rr < 2; rr++) {
        int n = wn + rr * 32;
        u16x8 o;
#pragma unroll
        for (int j = 0; j < 8; j++) o[j] = f2bf(tile[wk + j][n]);
        *(u16x8*)(Wt + (size_t)(n0 + n) * 1024 + k0 + wk) = o;
    }
}

// ---------------------- merged 128x128 GEMM (qkv + sw) ----------------------
__global__ __launch_bounds__(256, 2) void gemm01_k(const unsigned short* __restrict__ xb,
                                                   const unsigned short* __restrict__ wqkvt,
                                                   const float* __restrict__ bqkv,
                                                   const unsigned short* __restrict__ sbb,
                                                   const unsigned short* __restrict__ wst,
                                                   const float* __restrict__ bs,
                                                   unsigned short* __restrict__ q,
                                                   unsigned short* __restrict__ kk_,
                                                   unsigned short* __restrict__ vt,
                                                   float* __restrict__ swf) {
    __shared__ unsigned short lA[2][8192];   // [128 m][64 k] per buf
    __shared__ unsigned short lB[2][8192];   // [128 n][64 k] per buf
    const int blk = blockIdx.x, t = threadIdx.x;
    const int wave = t >> 6, lane = t & 63, c = lane & 15, g = lane >> 4;
    const int wr = (wave >> 1) * 64, wc = (wave & 1) * 64;

    const unsigned short* A;
    const unsigned short* Bt;
    const float* bias;
    int bn0, bm0, epi;
    if (blk < 384) { A = xb;  Bt = wqkvt; bias = bqkv; epi = 0;
                     bn0 = (blk % 24) * 128; bm0 = (blk / 24) * 128; }
    else           { int bb = blk - 384; A = sbb; Bt = wst; bias = bs; epi = 1;
                     bn0 = (bb & 7) * 128; bm0 = (bb >> 3) * 128; }

    size_t aoff[4], boff[4];
#pragma unroll
    for (int j = 0; j < 4; j++) {
        int s = j * 256 + t, row = s >> 3, ch = (s & 7) ^ (row & 7);
        aoff[j] = (size_t)(bm0 + row) * 1024 + ch * 8;
        boff[j] = (size_t)(bn0 + row) * 1024 + ch * 8;
    }
    char* lAb0 = (char*)lA[0]; char* lBb0 = (char*)lB[0];

#define GS128(buf, kt)                                                                    \
    do {                                                                                  \
        _Pragma("unroll")                                                                 \
        for (int j = 0; j < 4; j++)                                                       \
            gld_lds16(A + aoff[j] + (kt), lAb0 + (buf) * 16384 + j * 4096 + wave * 1024); \
        _Pragma("unroll")                                                                 \
        for (int j = 0; j < 4; j++)                                                       \
            gld_lds16(Bt + boff[j] + (kt), lBb0 + (buf) * 16384 + j * 4096 + wave * 1024);\
    } while (0)

    f32x4 acc[4][4];
#pragma unroll
    for (int i = 0; i < 4; i++)
#pragma unroll
        for (int j = 0; j < 4; j++) acc[i][j] = {0.f, 0.f, 0.f, 0.f};

    GS128(0, 0);
    for (int ks = 0; ks < 16; ++ks) {
        __syncthreads();
        if (ks < 15) GS128((ks + 1) & 1, (ks + 1) * 64);
        const char* aB = lAb0 + (ks & 1) * 16384;
        const char* bB = lBb0 + (ks & 1) * 16384;
#pragma unroll
        for (int kk2 = 0; kk2 < 2; ++kk2) {
            s16x8 af[4], bfr[4];
#pragma unroll
            for (int i = 0; i < 4; i++) {
                int r_ = wr + i * 16 + c;
                af[i] = *(const s16x8*)(aB + r_ * 128 + (((kk2 * 4 + g) ^ (r_ & 7)) << 4));
            }
#pragma unroll
            for (int j = 0; j < 4; j++) {
                int r_ = wc + j * 16 + c;
                bfr[j] = *(const s16x8*)(bB + r_ * 128 + (((kk2 * 4 + g) ^ (r_ & 7)) << 4));
            }
            __builtin_amdgcn_s_setprio(1);
#pragma unroll
            for (int i = 0; i < 4; i++)
#pragma unroll
                for (int j = 0; j < 4; j++)
                    acc[i][j] = mfma16(af[i], bfr[j], acc[i][j]);
            __builtin_amdgcn_s_setprio(0);
        }
    }
#undef GS128

#pragma unroll
    for (int i = 0; i < 4; i++) {
#pragma unroll
        for (int j = 0; j < 4; j++) {
            const int n = bn0 + wc + j * 16 + c;
            const float bv = bias[n];
#pragma unroll
            for (int r = 0; r < 4; r++) {
                const int m = bm0 + wr + i * 16 + g * 4 + r;
                float v = acc[i][j][r] + bv;
                if (epi == 0) {
                    const int sel = n >> 10, h = (n >> 6) & 15, d = n & 63;
                    const int b_ = m >> 10, l_ = m & 1023;
                    const size_t bh = (size_t)((b_ << 4) + h);
                    unsigned short hv = f2bf(v);
                    if (sel == 0)      q[(bh * 1024 + l_) * 64 + d] = hv;
                    else if (sel == 1) kk_[(bh * 1024 + l_) * 64 + d] = hv;
                    else               vt[(bh * 64 + d) * 1024 + l_] = hv;
                } else {
                    swf[(size_t)m * 1024 + n] = v;
                }
            }
        }
    }
}

// ---------------------------- out GEMM (64x128) -----------------------------
__global__ __launch_bounds__(256, 3) void gemmo_k(const unsigned short* __restrict__ A,
                                                  const unsigned short* __restrict__ Bt,
                                                  const float* __restrict__ bias,
                                                  float* __restrict__ outf) {
    __shared__ unsigned short lA[2][4096];
    __shared__ unsigned short lB[2][8192];
    const int t = threadIdx.x;
    const int wave = t >> 6, lane = t & 63, c = lane & 15, g = lane >> 4;
    const int bn0 = blockIdx.x * 128, bm0 = blockIdx.y * 64;
    const int wc = wave * 32;

    size_t aoff[2], boff[4];
#pragma unroll
    for (int j = 0; j < 2; j++) {
        int s = j * 256 + t, row = s >> 3, ch = (s & 7) ^ (row & 7);
        aoff[j] = (size_t)(bm0 + row) * 1024 + ch * 8;
    }
#pragma unroll
    for (int j = 0; j < 4; j++) {
        int s = j * 256 + t, row = s >> 3, ch = (s & 7) ^ (row & 7);
        boff[j] = (size_t)(bn0 + row) * 1024 + ch * 8;
    }
    char* lAb0 = (char*)lA[0]; char* lBb0 = (char*)lB[0];

#define GSTAGE(buf, kt)                                                                  \
    do {                                                                                 \
        _Pragma("unroll")                                                                \
        for (int j = 0; j < 2; j++)                                                      \
            gld_lds16(A + aoff[j] + (kt), lAb0 + (buf) * 8192 + j * 4096 + wave * 1024); \
        _Pragma("unroll")                                                                \
        for (int j = 0; j < 4; j++)                                                      \
            gld_lds16(Bt + boff[j] + (kt), lBb0 + (buf) * 16384 + j * 4096 + wave * 1024);\
    } while (0)

    f32x4 acc[4][2];
#pragma unroll
    for (int i = 0; i < 4; i++)
#pragma unroll
        for (int j = 0; j < 2; j++) acc[i][j] = {0.f, 0.f, 0.f, 0.f};

    GSTAGE(0, 0);
    for (int ks = 0; ks < 16; ++ks) {
        __syncthreads();
        if (ks < 15) GSTAGE((ks + 1) & 1, (ks + 1) * 64);
        const char* aB = lAb0 + (ks & 1) * 8192;
        const char* bB = lBb0 + (ks & 1) * 16384;
#pragma unroll
        for (int kk2 = 0; kk2 < 2; ++kk2) {
            s16x8 af[4], bfr[2];
#pragma unroll
            for (int i = 0; i < 4; i++) {
                int r_ = i * 16 + c;
                af[i] = *(const s16x8*)(aB + r_ * 128 + (((kk2 * 4 + g) ^ (r_ & 7)) << 4));
            }
#pragma unroll
            for (int j = 0; j < 2; j++) {
                int r_ = wc + j * 16 + c;
                bfr[j] = *(const s16x8*)(bB + r_ * 128 + (((kk2 * 4 + g) ^ (r_ & 7)) << 4));
            }
            __builtin_amdgcn_s_setprio(1);
#pragma unroll
            for (int i = 0; i < 4; i++)
#pragma unroll
                for (int j = 0; j < 2; j++)
                    acc[i][j] = mfma16(af[i], bfr[j], acc[i][j]);
            __builtin_amdgcn_s_setprio(0);
        }
    }
#undef GSTAGE

#pragma unroll
    for (int i = 0; i < 4; i++) {
#pragma unroll
        for (int j = 0; j < 2; j++) {
            const int n = bn0 + wc + j * 16 + c;
            const float bv = bias[n];
#pragma unroll
            for (int r = 0; r < 4; r++) {
                const int m = bm0 + i * 16 + g * 4 + r;
                outf[(size_t)m * 1024 + n] = acc[i][j][r] + bv;
            }
        }
    }
}

// ------------------------------ attention ----------------------------------
// STATIC-MAX softmax: P = exp2(z - 16); shift is exact pow2 scaling and
// cancels in acc/l. No max tracking, no cross-lane reduce, uniform control.
__global__ __launch_bounds__(256, 2) void attn_k(const unsigned short* __restrict__ q,
                                                 const unsigned short* __restrict__ k,
                                                 const unsigned short* __restrict__ vt,
                                                 const float* __restrict__ sw,
                                                 unsigned short* __restrict__ ctx) {
    __shared__ unsigned short kbuf[2][4096];         // [64 kv][64 hd] swizzled
    __shared__ unsigned short vbuf[2][4096];         // [64 d][64 kv] swizzled
    __shared__ unsigned short lP[4][640];            // per wave: 16 q-rows x 40 (pad)
    const int t = threadIdx.x, wave = t >> 6, lane = t & 63, c = lane & 15, g = lane >> 4;
    const int blk = blockIdx.x;
    const int qt = blk & 15, bh = blk >> 4, b_ = bh >> 4, h = bh & 15;
    const int qr = qt * 64 + wave * 16;

    const unsigned short* qbase = q + ((size_t)bh * 1024 + qr) * 64;
    s16x8 qf0 = *(const s16x8*)(qbase + (size_t)c * 64 + g * 8);
    s16x8 qf1 = *(const s16x8*)(qbase + (size_t)c * 64 + 32 + g * 8);

    const unsigned short* kg = k + (size_t)bh * 65536;     // [1024][64]
    const unsigned short* vg = vt + (size_t)bh * 65536;    // [64][1024]
    const float* swrow = sw + ((size_t)b_ * 1024 + qr + c) * 1024;

    const int s0 = wave * 128 + lane, s1 = s0 + 64;
    const int r0 = s0 >> 3, ch0 = (s0 & 7) ^ (r0 & 7);
    const int r1 = s1 >> 3, ch1 = (s1 & 7) ^ (r1 & 7);

    const float SC  = 0.125f * 1.4426950408889634f;  // (1/sqrt(64)) * log2(e)
    const float L2E = 1.4426950408889634f;
    const float SHIFT = 16.0f;                       // static max (exp2 domain)

    const short one_bf = (short)0x3F80;              // bf16 1.0
    const s16x8 ones = { one_bf, one_bf, one_bf, one_bf, one_bf, one_bf, one_bf, one_bf };

    f32x4 acc[4];                    // acc[nf][r] = ctx^T[d = nf*16+4g+r][q = c]
    f32x4 accl = {0.f, 0.f, 0.f, 0.f};   // accl[*] = l for q-row c
#pragma unroll
    for (int nf = 0; nf < 4; nf++) acc[nf] = {0.f, 0.f, 0.f, 0.f};
    unsigned short* wp = lP[wave];
    const int swz = (c & 7);

#define STAGE(buf, kv0)                                                                     \
    do {                                                                                    \
        gld_lds16(kg + (size_t)((kv0) + r0) * 64 + ch0 * 8, (char*)kbuf[buf] + wave * 2048);            \
        gld_lds16(kg + (size_t)((kv0) + r1) * 64 + ch1 * 8, (char*)kbuf[buf] + wave * 2048 + 1024);     \
        gld_lds16(vg + (size_t)r0 * 1024 + (kv0) + ch0 * 8, (char*)vbuf[buf] + wave * 2048);            \
        gld_lds16(vg + (size_t)r1 * 1024 + (kv0) + ch1 * 8, (char*)vbuf[buf] + wave * 2048 + 1024);     \
    } while (0)

    STAGE(0, 0);
    __syncthreads();

    int cur = 0;
    for (int it = 0; it < 16; ++it) {
        const int kv0 = it * 64;
        if (it < 15) STAGE(cur ^ 1, kv0 + 64);
        float4 sws[4];
#pragma unroll
        for (int j = 0; j < 4; j++) sws[j] = *(const float4*)(swrow + kv0 + j * 16 + 4 * g);

        const char* kB = (const char*)kbuf[cur];
        const char* vB = (const char*)vbuf[cur];
#pragma unroll
        for (int ks2 = 0; ks2 < 2; ++ks2) {
            s16x8 kc0 = *(const s16x8*)(kB + ((ks2 * 32 + c) << 7) + (((0 + g) ^ swz) << 4));
            s16x8 kc1 = *(const s16x8*)(kB + ((ks2 * 32 + c) << 7) + (((4 + g) ^ swz) << 4));
            s16x8 kc2 = *(const s16x8*)(kB + ((ks2 * 32 + 16 + c) << 7) + (((0 + g) ^ swz) << 4));
            s16x8 kc3 = *(const s16x8*)(kB + ((ks2 * 32 + 16 + c) << 7) + (((4 + g) ^ swz) << 4));

            __builtin_amdgcn_s_setprio(1);
            f32x4 ss0 = {0.f, 0.f, 0.f, 0.f}, ss1 = {0.f, 0.f, 0.f, 0.f};
            ss0 = mfma16(kc0, qf0, ss0); ss0 = mfma16(kc1, qf1, ss0);
            ss1 = mfma16(kc2, qf0, ss1); ss1 = mfma16(kc3, qf1, ss1);
            __builtin_amdgcn_s_setprio(0);

            float4 swa = sws[2 * ks2], swb = sws[2 * ks2 + 1];
            float p0[4], p1[4];
#pragma unroll
            for (int r = 0; r < 4; r++) {
                float z0 = ss0[r] * SC + ((&swa.x)[r] * L2E - SHIFT);
                float z1 = ss1[r] * SC + ((&swb.x)[r] * L2E - SHIFT);
                p0[r] = __builtin_amdgcn_exp2f(z0);
                p1[r] = __builtin_amdgcn_exp2f(z1);
            }

            u16x4 w0, w1;
#pragma unroll
            for (int r = 0; r < 4; r++) { w0[r] = f2bf(p0[r]); w1[r] = f2bf(p1[r]); }
            *(u16x4*)(wp + c * 40 + 4 * g) = w0;
            *(u16x4*)(wp + c * 40 + 16 + 4 * g) = w1;
            s16x8 ap = *(const s16x8*)((const char*)wp + c * 80 + g * 16);

            __builtin_amdgcn_s_setprio(1);
            accl = mfma16(ones, ap, accl);               // l += row-sum of P
#pragma unroll
            for (int nf = 0; nf < 4; nf++) {
                s16x8 vf = *(const s16x8*)(vB + ((nf * 16 + c) << 7) + ((((ks2 << 2) + g) ^ swz) << 4));
                acc[nf] = mfma16(vf, ap, acc[nf]);       // ctx^T += V^T . P^T
            }
            __builtin_amdgcn_s_setprio(0);
        }
        __syncthreads();
        cur ^= 1;
    }
#undef STAGE

    float inv = 1.0f / accl[0];
#pragma unroll
    for (int nf = 0; nf < 4; nf++)
#pragma unroll
        for (int r = 0; r < 4; r++) acc[nf][r] *= inv;

    __syncthreads();
    float* scr = (wave < 2) ? ((float*)kbuf + wave * 1088)
                            : ((float*)vbuf + (wave - 2) * 1088);   // 64 x 17 f32
#pragma unroll
    for (int nf = 0; nf < 4; nf++)
#pragma unroll
        for (int r = 0; r < 4; r++)
            scr[(nf * 16 + 4 * g + r) * 17 + c] = acc[nf][r];
    __syncthreads();
    u16x8 o0, o1;
#pragma unroll
    for (int j = 0; j < 8; j++) o0[j] = f2bf(scr[(g * 16 + j) * 17 + c]);
#pragma unroll
    for (int j = 0; j < 8; j++) o1[j] = f2bf(scr[(g * 16 + 8 + j) * 17 + c]);
    unsigned short* dst = ctx + ((size_t)(b_ << 10) + qr + c) * 1024 + (h << 6) + g * 16;
    *(u16x8*)dst = o0;
    *(u16x8*)(dst + 8) = o1;
}

// ------------------------------- launch ------------------------------------
extern "C" void kernel_launch(void* const* d_in, const int* in_sizes, int n_in,
                              void* d_out, int out_size, void* d_ws, size_t ws_size,
                              hipStream_t stream) {
    const float* x    = (const float*)d_in[0];
    const float* sb   = (const float*)d_in[1];
    const float* Wqkv = (const float*)d_in[2];
    const float* bqkv = (const float*)d_in[3];
    const float* Ws   = (const float*)d_in[4];
    const float* bs   = (const float*)d_in[5];
    const float* Wo   = (const float*)d_in[6];
    const float* bo   = (const float*)d_in[7];
    float* out = (float*)d_out;

    char* ws = (char*)d_ws;
    unsigned short* xb    = (unsigned short*)(ws);
    unsigned short* sbb   = (unsigned short*)(ws + ((size_t)4 << 20));
    unsigned short* wqkvt = (unsigned short*)(ws + ((size_t)8 << 20));
    unsigned short* wst   = (unsigned short*)(ws + ((size_t)14 << 20));
    unsigned short* wot   = (unsigned short*)(ws + ((size_t)16 << 20));
    unsigned short* qb    = (unsigned short*)(ws + ((size_t)18 << 20));
    unsigned short* kb    = (unsigned short*)(ws + ((size_t)22 << 20));
    unsigned short* vtb   = (unsigned short*)(ws + ((size_t)26 << 20));
    float*          swf   = (float*)        (ws + ((size_t)30 << 20));
    unsigned short* ctxb  = (unsigned short*)(ws + ((size_t)38 << 20));

    prep_k<<<dim3(3328), dim3(256), 0, stream>>>(x, sb, Wqkv, Ws, Wo,
                                                 xb, sbb, wqkvt, wst, wot);
    gemm01_k<<<dim3(512), dim3(256), 0, stream>>>(xb, wqkvt, bqkv, sbb, wst, bs,
                                                  qb, kb, vtb, swf);
    attn_k<<<dim3(512), dim3(256), 0, stream>>>(qb, kb, vtb, swf, ctxb);
    gemmo_k<<<dim3(8, 32), dim3(256), 0, stream>>>(ctxb, wot, bo, out);
}

// Round 9
// 81.353 us; speedup vs baseline: 1.1687x; 1.0289x over previous
//
#include <hip/hip_runtime.h>
#include <stdint.h>
#include <stddef.h>

// ---------------------------------------------------------------------------
// StructureAwareAttention  (B=2, L=1024, D=1024, H=16, HD=64)
//   prep: cvt x,sb -> bf16; transpose Wqkv/Ws/Wo -> [N][K] bf16   (1 kernel)
//   gemm01 (merged, 128x128 BK=64 dbuf, 512 blocks = 2/CU exact):
//       qkv = x@Wqkv+bqkv -> q,k [B,H,L,64] bf16, v^T [B,H,64,L] bf16
//       sw  = sb@Ws+bs -> f32 [B,L,L]
//   attn: 512 threads / 8 waves: waves 0-3 sweep KV[0,512), waves 4-7 sweep
//       KV[512,1024) for the SAME 64 q-rows (per-group dbuf swizzled K/V LDS).
//       Static-max softmax (P=exp2(z-16)) -> partials merge by pure addition
//       in LDS at the end. 74KB LDS -> 2 blocks/CU -> 4 waves/SIMD.
//   out = ctx@Wo + bo -> f32   (64x128 BK=64 dbuf)
// Workspace:
//   0: xb 4MB | 4MB: sbb 4MB | 8MB: Wqkv^T 6MB | 14MB: Ws^T 2MB | 16MB: Wo^T 2MB
//   18MB: q 4MB | 22MB: k 4MB | 26MB: v^T 4MB | 30MB: sw(f32) 8MB | 38MB: ctx 4MB
// ---------------------------------------------------------------------------

typedef float f32x4 __attribute__((ext_vector_type(4)));
typedef short s16x8 __attribute__((ext_vector_type(8)));
typedef unsigned short u16x8 __attribute__((ext_vector_type(8)));
typedef unsigned short u16x4 __attribute__((ext_vector_type(4)));

__device__ inline unsigned short f2bf(float f) {          // RNE f32 -> bf16
    unsigned u = __builtin_bit_cast(unsigned, f);
    u += 0x7fffu + ((u >> 16) & 1u);
    return (unsigned short)(u >> 16);
}

__device__ inline f32x4 mfma16(s16x8 a, s16x8 b, f32x4 c) {
    return __builtin_amdgcn_mfma_f32_16x16x32_bf16(a, b, c, 0, 0, 0);
}

__device__ inline void gld_lds16(const void* g, const void* lds_base) {
    __builtin_amdgcn_global_load_lds(
        (const __attribute__((address_space(1))) void*)(uintptr_t)g,
        (__attribute__((address_space(3))) void*)(unsigned)(uintptr_t)lds_base,
        16, 0, 0);
}

// ------------------------------ prep ---------------------------------------
__global__ __launch_bounds__(256) void prep_k(const float* __restrict__ x,
                                              const float* __restrict__ sb,
                                              const float* __restrict__ Wqkv,
                                              const float* __restrict__ Ws,
                                              const float* __restrict__ Wo,
                                              unsigned short* __restrict__ xb,
                                              unsigned short* __restrict__ sbb,
                                              unsigned short* __restrict__ wqkvt,
                                              unsigned short* __restrict__ wst,
                                              unsigned short* __restrict__ wot) {
    __shared__ float tile[64][65];
    const int blk = blockIdx.x, t = threadIdx.x;
    if (blk < 2048) {
        const float* src = (blk < 1024) ? x : sb;
        unsigned short* dst = (blk < 1024) ? xb : sbb;
        int i = (blk & 1023) * 256 + t;
        const float4* s4 = (const float4*)src;
        float4 a = s4[2 * i], b = s4[2 * i + 1];
        u16x8 o;
        o[0] = f2bf(a.x); o[1] = f2bf(a.y); o[2] = f2bf(a.z); o[3] = f2bf(a.w);
        o[4] = f2bf(b.x); o[5] = f2bf(b.y); o[6] = f2bf(b.z); o[7] = f2bf(b.w);
        *(u16x8*)(dst + (size_t)i * 8) = o;
        return;
    }
    int tt = blk - 2048;
    const float* W; unsigned short* Wt; int N, n0, k0;
    if (tt < 768)       { W = Wqkv; Wt = wqkvt; N = 3072; n0 = (tt % 48) * 64; k0 = (tt / 48) * 64; }
    else if (tt < 1024) { tt -= 768;  W = Ws; Wt = wst; N = 1024; n0 = (tt & 15) * 64; k0 = (tt >> 4) * 64; }
    else                { tt -= 1024; W = Wo; Wt = wot; N = 1024; n0 = (tt & 15) * 64; k0 = (tt >> 4) * 64; }
    const int lr = t >> 4, lc = (t & 15) * 4;
#pragma unroll
    for (int rr = 0; rr < 4; rr++) {
        int r = lr + rr * 16;
        float4 v = *(const float4*)(W + (size_t)(k0 + r) * N + n0 + lc);
        tile[r][lc] = v.x; tile[r][lc + 1] = v.y; tile[r][lc + 2] = v.z; tile[r][lc + 3] = v.w;
    }
    __syncthreads();
    const int wn = t >> 3, wk = (t & 7) * 8;
#pragma unroll
    for (int rr = 0; rr < 2; rr++) {
        int n = wn + rr * 32;
        u16x8 o;
#pragma unroll
        for (int j = 0; j < 8; j++) o[j] = f2bf(tile[wk + j][n]);
        *(u16x8*)(Wt + (size_t)(n0 + n) * 1024 + k0 + wk) = o;
    }
}

// ---------------------- merged 128x128 GEMM (qkv + sw) ----------------------
__global__ __launch_bounds__(256, 2) void gemm01_k(const unsigned short* __restrict__ xb,
                                                   const unsigned short* __restrict__ wqkvt,
                                                   const float* __restrict__ bqkv,
                                                   const unsigned short* __restrict__ sbb,
                                                   const unsigned short* __restrict__ wst,
                                                   const float* __restrict__ bs,
                                                   unsigned short* __restrict__ q,
                                                   unsigned short* __restrict__ kk_,
                                                   unsigned short* __restrict__ vt,
                                                   float* __restrict__ swf) {
    __shared__ unsigned short lA[2][8192];   // [128 m][64 k] per buf
    __shared__ unsigned short lB[2][8192];   // [128 n][64 k] per buf
    const int blk = blockIdx.x, t = threadIdx.x;
    const int wave = t >> 6, lane = t & 63, c = lane & 15, g = lane >> 4;
    const int wr = (wave >> 1) * 64, wc = (wave & 1) * 64;

    const unsigned short* A;
    const unsigned short* Bt;
    const float* bias;
    int bn0, bm0, epi;
    if (blk < 384) { A = xb;  Bt = wqkvt; bias = bqkv; epi = 0;
                     bn0 = (blk % 24) * 128; bm0 = (blk / 24) * 128; }
    else           { int bb = blk - 384; A = sbb; Bt = wst; bias = bs; epi = 1;
                     bn0 = (bb & 7) * 128; bm0 = (bb >> 3) * 128; }

    size_t aoff[4], boff[4];
#pragma unroll
    for (int j = 0; j < 4; j++) {
        int s = j * 256 + t, row = s >> 3, ch = (s & 7) ^ (row & 7);
        aoff[j] = (size_t)(bm0 + row) * 1024 + ch * 8;
        boff[j] = (size_t)(bn0 + row) * 1024 + ch * 8;
    }
    char* lAb0 = (char*)lA[0]; char* lBb0 = (char*)lB[0];

#define GS128(buf, kt)                                                                    \
    do {                                                                                  \
        _Pragma("unroll")                                                                 \
        for (int j = 0; j < 4; j++)                                                       \
            gld_lds16(A + aoff[j] + (kt), lAb0 + (buf) * 16384 + j * 4096 + wave * 1024); \
        _Pragma("unroll")                                                                 \
        for (int j = 0; j < 4; j++)                                                       \
            gld_lds16(Bt + boff[j] + (kt), lBb0 + (buf) * 16384 + j * 4096 + wave * 1024);\
    } while (0)

    f32x4 acc[4][4];
#pragma unroll
    for (int i = 0; i < 4; i++)
#pragma unroll
        for (int j = 0; j < 4; j++) acc[i][j] = {0.f, 0.f, 0.f, 0.f};

    GS128(0, 0);
    for (int ks = 0; ks < 16; ++ks) {
        __syncthreads();
        if (ks < 15) GS128((ks + 1) & 1, (ks + 1) * 64);
        const char* aB = lAb0 + (ks & 1) * 16384;
        const char* bB = lBb0 + (ks & 1) * 16384;
#pragma unroll
        for (int kk2 = 0; kk2 < 2; ++kk2) {
            s16x8 af[4], bfr[4];
#pragma unroll
            for (int i = 0; i < 4; i++) {
                int r_ = wr + i * 16 + c;
                af[i] = *(const s16x8*)(aB + r_ * 128 + (((kk2 * 4 + g) ^ (r_ & 7)) << 4));
            }
#pragma unroll
            for (int j = 0; j < 4; j++) {
                int r_ = wc + j * 16 + c;
                bfr[j] = *(const s16x8*)(bB + r_ * 128 + (((kk2 * 4 + g) ^ (r_ & 7)) << 4));
            }
            __builtin_amdgcn_s_setprio(1);
#pragma unroll
            for (int i = 0; i < 4; i++)
#pragma unroll
                for (int j = 0; j < 4; j++)
                    acc[i][j] = mfma16(af[i], bfr[j], acc[i][j]);
            __builtin_amdgcn_s_setprio(0);
        }
    }
#undef GS128

#pragma unroll
    for (int i = 0; i < 4; i++) {
#pragma unroll
        for (int j = 0; j < 4; j++) {
            const int n = bn0 + wc + j * 16 + c;
            const float bv = bias[n];
#pragma unroll
            for (int r = 0; r < 4; r++) {
                const int m = bm0 + wr + i * 16 + g * 4 + r;
                float v = acc[i][j][r] + bv;
                if (epi == 0) {
                    const int sel = n >> 10, h = (n >> 6) & 15, d = n & 63;
                    const int b_ = m >> 10, l_ = m & 1023;
                    const size_t bh = (size_t)((b_ << 4) + h);
                    unsigned short hv = f2bf(v);
                    if (sel == 0)      q[(bh * 1024 + l_) * 64 + d] = hv;
                    else if (sel == 1) kk_[(bh * 1024 + l_) * 64 + d] = hv;
                    else               vt[(bh * 64 + d) * 1024 + l_] = hv;
                } else {
                    swf[(size_t)m * 1024 + n] = v;
                }
            }
        }
    }
}

// ---------------------------- out GEMM (64x128) -----------------------------
__global__ __launch_bounds__(256, 3) void gemmo_k(const unsigned short* __restrict__ A,
                                                  const unsigned short* __restrict__ Bt,
                                                  const float* __restrict__ bias,
                                                  float* __restrict__ outf) {
    __shared__ unsigned short lA[2][4096];
    __shared__ unsigned short lB[2][8192];
    const int t = threadIdx.x;
    const int wave = t >> 6, lane = t & 63, c = lane & 15, g = lane >> 4;
    const int bn0 = blockIdx.x * 128, bm0 = blockIdx.y * 64;
    const int wc = wave * 32;

    size_t aoff[2], boff[4];
#pragma unroll
    for (int j = 0; j < 2; j++) {
        int s = j * 256 + t, row = s >> 3, ch = (s & 7) ^ (row & 7);
        aoff[j] = (size_t)(bm0 + row) * 1024 + ch * 8;
    }
#pragma unroll
    for (int j = 0; j < 4; j++) {
        int s = j * 256 + t, row = s >> 3, ch = (s & 7) ^ (row & 7);
        boff[j] = (size_t)(bn0 + row) * 1024 + ch * 8;
    }
    char* lAb0 = (char*)lA[0]; char* lBb0 = (char*)lB[0];

#define GSTAGE(buf, kt)                                                                  \
    do {                                                                                 \
        _Pragma("unroll")                                                                \
        for (int j = 0; j < 2; j++)                                                      \
            gld_lds16(A + aoff[j] + (kt), lAb0 + (buf) * 8192 + j * 4096 + wave * 1024); \
        _Pragma("unroll")                                                                \
        for (int j = 0; j < 4; j++)                                                      \
            gld_lds16(Bt + boff[j] + (kt), lBb0 + (buf) * 16384 + j * 4096 + wave * 1024);\
    } while (0)

    f32x4 acc[4][2];
#pragma unroll
    for (int i = 0; i < 4; i++)
#pragma unroll
        for (int j = 0; j < 2; j++) acc[i][j] = {0.f, 0.f, 0.f, 0.f};

    GSTAGE(0, 0);
    for (int ks = 0; ks < 16; ++ks) {
        __syncthreads();
        if (ks < 15) GSTAGE((ks + 1) & 1, (ks + 1) * 64);
        const char* aB = lAb0 + (ks & 1) * 8192;
        const char* bB = lBb0 + (ks & 1) * 16384;
#pragma unroll
        for (int kk2 = 0; kk2 < 2; ++kk2) {
            s16x8 af[4], bfr[2];
#pragma unroll
            for (int i = 0; i < 4; i++) {
                int r_ = i * 16 + c;
                af[i] = *(const s16x8*)(aB + r_ * 128 + (((kk2 * 4 + g) ^ (r_ & 7)) << 4));
            }
#pragma unroll
            for (int j = 0; j < 2; j++) {
                int r_ = wc + j * 16 + c;
                bfr[j] = *(const s16x8*)(bB + r_ * 128 + (((kk2 * 4 + g) ^ (r_ & 7)) << 4));
            }
            __builtin_amdgcn_s_setprio(1);
#pragma unroll
            for (int i = 0; i < 4; i++)
#pragma unroll
                for (int j = 0; j < 2; j++)
                    acc[i][j] = mfma16(af[i], bfr[j], acc[i][j]);
            __builtin_amdgcn_s_setprio(0);
        }
    }
#undef GSTAGE

#pragma unroll
    for (int i = 0; i < 4; i++) {
#pragma unroll
        for (int j = 0; j < 2; j++) {
            const int n = bn0 + wc + j * 16 + c;
            const float bv = bias[n];
#pragma unroll
            for (int r = 0; r < 4; r++) {
                const int m = bm0 + i * 16 + g * 4 + r;
                outf[(size_t)m * 1024 + n] = acc[i][j][r] + bv;
            }
        }
    }
}

// ------------------------------ attention ----------------------------------
// 512 threads / 8 waves. Waves 0-3 (group 0) sweep KV[0,512), waves 4-7
// (group 1) sweep KV[512,1024) for the SAME 64 q-rows. Per-group dbuf K/V LDS
// (swizzled both sides), KVBLK=64, 8 iters. Static-max softmax P=exp2(z-16):
// no max state -> partials are plain sums; group 1 parks acc^T + l in dead
// staging LDS, group 0 adds, normalizes, transposes, writes ctx.
__global__ __launch_bounds__(512, 4) void attn_k(const unsigned short* __restrict__ q,
                                                 const unsigned short* __restrict__ k,
                                                 const unsigned short* __restrict__ vt,
                                                 const float* __restrict__ sw,
                                                 unsigned short* __restrict__ ctx) {
    __shared__ unsigned short kbuf[2][2][4096];      // [group][buf][64kv x 64hd] 32KB
    __shared__ unsigned short vbuf[2][2][4096];      // [group][buf][64d x 64kv]  32KB
    __shared__ unsigned short lP[8][640];            // per wave: 16 q x 40 (pad) 10KB
    const int t = threadIdx.x, wave = t >> 6, lane = t & 63, c = lane & 15, g = lane >> 4;
    const int grp = wave >> 2, wl = wave & 3;
    const int blk = blockIdx.x;
    const int qt = blk & 15, bh = blk >> 4, b_ = bh >> 4, h = bh & 15;
    const int qr = qt * 64 + wl * 16;

    const unsigned short* qbase = q + ((size_t)bh * 1024 + qr) * 64;
    s16x8 qf0 = *(const s16x8*)(qbase + (size_t)c * 64 + g * 8);
    s16x8 qf1 = *(const s16x8*)(qbase + (size_t)c * 64 + 32 + g * 8);

    const unsigned short* kg  = k + (size_t)bh * 65536 + (size_t)grp * 512 * 64;  // rows kv
    const unsigned short* vgb = vt + (size_t)bh * 65536 + grp * 512;              // cols kv
    const float* swrow = sw + ((size_t)b_ * 1024 + qr + c) * 1024 + grp * 512;

    const int s0 = wl * 128 + lane, s1 = s0 + 64;
    const int r0 = s0 >> 3, ch0 = (s0 & 7) ^ (r0 & 7);
    const int r1 = s1 >> 3, ch1 = (s1 & 7) ^ (r1 & 7);

    const float SC  = 0.125f * 1.4426950408889634f;  // (1/sqrt(64)) * log2(e)
    const float L2E = 1.4426950408889634f;
    const float SHIFT = 16.0f;                       // static max (exp2 domain)

    const short one_bf = (short)0x3F80;              // bf16 1.0
    const s16x8 ones = { one_bf, one_bf, one_bf, one_bf, one_bf, one_bf, one_bf, one_bf };

    f32x4 acc[4];                    // acc[nf][r] = ctx^T[d = nf*16+4g+r][q = c]
    f32x4 accl = {0.f, 0.f, 0.f, 0.f};
#pragma unroll
    for (int nf = 0; nf < 4; nf++) acc[nf] = {0.f, 0.f, 0.f, 0.f};
    unsigned short* wp = lP[wave];
    const int swz = (c & 7);

    char* kgrp = (char*)kbuf + grp * 16384;          // this group's K dbuf (2x8KB)
    char* vgrp = (char*)vbuf + grp * 16384;

#define STAGE(buf, kv0)                                                                     \
    do {                                                                                    \
        gld_lds16(kg + (size_t)((kv0) + r0) * 64 + ch0 * 8, kgrp + (buf) * 8192 + wl * 2048);          \
        gld_lds16(kg + (size_t)((kv0) + r1) * 64 + ch1 * 8, kgrp + (buf) * 8192 + wl * 2048 + 1024);   \
        gld_lds16(vgb + (size_t)r0 * 1024 + (kv0) + ch0 * 8, vgrp + (buf) * 8192 + wl * 2048);         \
        gld_lds16(vgb + (size_t)r1 * 1024 + (kv0) + ch1 * 8, vgrp + (buf) * 8192 + wl * 2048 + 1024);  \
    } while (0)

    STAGE(0, 0);
    __syncthreads();

    int cur = 0;
    for (int it = 0; it < 8; ++it) {
        const int kv0 = it * 64;
        if (it < 7) STAGE(cur ^ 1, kv0 + 64);
        float4 sws[4];
#pragma unroll
        for (int j = 0; j < 4; j++) sws[j] = *(const float4*)(swrow + kv0 + j * 16 + 4 * g);

        const char* kB = kgrp + cur * 8192;
        const char* vB = vgrp + cur * 8192;
#pragma unroll
        for (int ks2 = 0; ks2 < 2; ++ks2) {
            s16x8 kc0 = *(const s16x8*)(kB + ((ks2 * 32 + c) << 7) + (((0 + g) ^ swz) << 4));
            s16x8 kc1 = *(const s16x8*)(kB + ((ks2 * 32 + c) << 7) + (((4 + g) ^ swz) << 4));
            s16x8 kc2 = *(const s16x8*)(kB + ((ks2 * 32 + 16 + c) << 7) + (((0 + g) ^ swz) << 4));
            s16x8 kc3 = *(const s16x8*)(kB + ((ks2 * 32 + 16 + c) << 7) + (((4 + g) ^ swz) << 4));

            __builtin_amdgcn_s_setprio(1);
            f32x4 ss0 = {0.f, 0.f, 0.f, 0.f}, ss1 = {0.f, 0.f, 0.f, 0.f};
            ss0 = mfma16(kc0, qf0, ss0); ss0 = mfma16(kc1, qf1, ss0);
            ss1 = mfma16(kc2, qf0, ss1); ss1 = mfma16(kc3, qf1, ss1);
            __builtin_amdgcn_s_setprio(0);

            float4 swa = sws[2 * ks2], swb = sws[2 * ks2 + 1];
            float p0[4], p1[4];
#pragma unroll
            for (int r = 0; r < 4; r++) {
                float z0 = ss0[r] * SC + ((&swa.x)[r] * L2E - SHIFT);
                float z1 = ss1[r] * SC + ((&swb.x)[r] * L2E - SHIFT);
                p0[r] = __builtin_amdgcn_exp2f(z0);
                p1[r] = __builtin_amdgcn_exp2f(z1);
            }

            u16x4 w0, w1;
#pragma unroll
            for (int r = 0; r < 4; r++) { w0[r] = f2bf(p0[r]); w1[r] = f2bf(p1[r]); }
            *(u16x4*)(wp + c * 40 + 4 * g) = w0;
            *(u16x4*)(wp + c * 40 + 16 + 4 * g) = w1;
            s16x8 ap = *(const s16x8*)((const char*)wp + c * 80 + g * 16);

            __builtin_amdgcn_s_setprio(1);
            accl = mfma16(ones, ap, accl);               // l += row-sum of P
#pragma unroll
            for (int nf = 0; nf < 4; nf++) {
                s16x8 vf = *(const s16x8*)(vB + ((nf * 16 + c) << 7) + ((((ks2 << 2) + g) ^ swz) << 4));
                acc[nf] = mfma16(vf, ap, acc[nf]);       // ctx^T += V^T . P^T
            }
            __builtin_amdgcn_s_setprio(0);
        }
        __syncthreads();
        cur ^= 1;
    }
#undef STAGE

    // ---- merge group 1 into group 0 (plain add: shared static shift) ----
    float* pscr = (float*)vbuf;                      // 8192 f32, staging dead
    if (grp == 1) {
        float* pw = pscr + wl * 1040;                // 64d x 16q + 16 l
#pragma unroll
        for (int nf = 0; nf < 4; nf++)
#pragma unroll
            for (int r = 0; r < 4; r++)
                pw[(nf * 16 + 4 * g + r) * 16 + c] = acc[nf][r];
        if (g == 0) pw[1024 + c] = accl[0];
    }
    __syncthreads();

    float* scr = (float*)kbuf + wl * 1088;           // 64 x 17 transpose scratch
    if (grp == 0) {
        float* pw = pscr + wl * 1040;
#pragma unroll
        for (int nf = 0; nf < 4; nf++)
#pragma unroll
            for (int r = 0; r < 4; r++)
                acc[nf][r] += pw[(nf * 16 + 4 * g + r) * 16 + c];
        float inv = 1.0f / (accl[0] + pw[1024 + c]);
#pragma unroll
        for (int nf = 0; nf < 4; nf++)
#pragma unroll
            for (int r = 0; r < 4; r++)
                scr[(nf * 16 + 4 * g + r) * 17 + c] = acc[nf][r] * inv;
    }
    __syncthreads();
    if (grp == 0) {
        u16x8 o0, o1;
#pragma unroll
        for (int j = 0; j < 8; j++) o0[j] = f2bf(scr[(g * 16 + j) * 17 + c]);
#pragma unroll
        for (int j = 0; j < 8; j++) o1[j] = f2bf(scr[(g * 16 + 8 + j) * 17 + c]);
        unsigned short* dst = ctx + ((size_t)(b_ << 10) + qr + c) * 1024 + (h << 6) + g * 16;
        *(u16x8*)dst = o0;
        *(u16x8*)(dst + 8) = o1;
    }
}

// ------------------------------- launch ------------------------------------
extern "C" void kernel_launch(void* const* d_in, const int* in_sizes, int n_in,
                              void* d_out, int out_size, void* d_ws, size_t ws_size,
                              hipStream_t stream) {
    const float* x    = (const float*)d_in[0];
    const float* sb   = (const float*)d_in[1];
    const float* Wqkv = (const float*)d_in[2];
    const float* bqkv = (const float*)d_in[3];
    const float* Ws   = (const float*)d_in[4];
    const float* bs   = (const float*)d_in[5];
    const float* Wo   = (const float*)d_in[6];
    const float* bo   = (const float*)d_in[7];
    float* out = (float*)d_out;

    char* ws = (char*)d_ws;
    unsigned short* xb    = (unsigned short*)(ws);
    unsigned short* sbb   = (unsigned short*)(ws + ((size_t)4 << 20));
    unsigned short* wqkvt = (unsigned short*)(ws + ((size_t)8 << 20));
    unsigned short* wst   = (unsigned short*)(ws + ((size_t)14 << 20));
    unsigned short* wot   = (unsigned short*)(ws + ((size_t)16 << 20));
    unsigned short* qb    = (unsigned short*)(ws + ((size_t)18 << 20));
    unsigned short* kb    = (unsigned short*)(ws + ((size_t)22 << 20));
    unsigned short* vtb   = (unsigned short*)(ws + ((size_t)26 << 20));
    float*          swf   = (float*)        (ws + ((size_t)30 << 20));
    unsigned short* ctxb  = (unsigned short*)(ws + ((size_t)38 << 20));

    prep_k<<<dim3(3328), dim3(256), 0, stream>>>(x, sb, Wqkv, Ws, Wo,
                                                 xb, sbb, wqkvt, wst, wot);
    gemm01_k<<<dim3(512), dim3(256), 0, stream>>>(xb, wqkvt, bqkv, sbb, wst, bs,
                                                  qb, kb, vtb, swf);
    attn_k<<<dim3(512), dim3(512), 0, stream>>>(qb, kb, vtb, swf, ctxb);
    gemmo_k<<<dim3(8, 32), dim3(256), 0, stream>>>(ctxb, wot, bo, out);
}